// Round 1
// baseline (340.960 us; speedup 1.0000x reference)
//
#include <hip/hip_runtime.h>

#define CUTOFF 1.6f
#define BLOCK 256
#define EPT 8
#define EPB (BLOCK * EPT)

struct f3 { float x, y, z; };

// K1: read Rij, write Rij passthrough, per-block short-range counts.
__global__ void __launch_bounds__(BLOCK) k1_count_copy(
    const float* __restrict__ Rij, float* __restrict__ outRij,
    int* __restrict__ counts, long E)
{
  long b = blockIdx.x;
  int t = threadIdx.x;
  long base = b * (long)EPB + (long)t * EPT;
  int cnt = 0;
  if (base < E) {  // E % 8 == 0 -> thread has all 8 edges or none
    const f3* rp = (const f3*)Rij;
    f3* op = (f3*)outRij;
#pragma unroll
    for (int k = 0; k < EPT; ++k) {
      f3 v = rp[base + k];
      op[base + k] = v;
      float s = sqrtf(v.x * v.x + v.y * v.y + v.z * v.z);
      cnt += (s <= CUTOFF) ? 1 : 0;
    }
  }
#pragma unroll
  for (int d = 32; d > 0; d >>= 1) cnt += __shfl_down(cnt, d, 64);
  __shared__ int ssum;
  if (t == 0) ssum = 0;
  __syncthreads();
  if ((t & 63) == 0) atomicAdd(&ssum, cnt);
  __syncthreads();
  if (t == 0) counts[b] = ssum;
}

// K2: single-block exclusive scan of block counts; writes n_sr (int to ws,
// float to out[10E]).
__global__ void __launch_bounds__(1024) k2_scan(
    int* __restrict__ counts, int nb, int* __restrict__ nsr,
    float* __restrict__ out_nsr)
{
  int t = threadIdx.x;
  int C = (nb + 1023) >> 10;
  int start = t * C;
  int end = min(start + C, nb);
  int sum = 0;
  for (int i = start; i < end; ++i) sum += counts[i];
  int lane = t & 63, wid = t >> 6;
  int v = sum;
#pragma unroll
  for (int d = 1; d < 64; d <<= 1) {
    int n = __shfl_up(v, d, 64);
    if (lane >= d) v += n;
  }
  __shared__ int wsum[16];
  if (lane == 63) wsum[wid] = v;
  __syncthreads();
  int woff = 0;
  for (int w = 0; w < wid; ++w) woff += wsum[w];
  int run = woff + v - sum;  // exclusive prefix of this thread
  for (int i = start; i < end; ++i) {
    int c = counts[i];
    counts[i] = run;
    run += c;
  }
  if (t == 1023) {  // run here == grand total
    nsr[0] = run;
    out_nsr[0] = (float)run;
  }
}

// K4: fill padding region [n_sr, E): Rij_sr rows = 0, idx_sr = -1.
__global__ void __launch_bounds__(256) k4_fill(
    float* __restrict__ out, const int* __restrict__ nsr, long E)
{
  long n = *nsr;
  long stride = (long)gridDim.x * blockDim.x;
  f3* sr = (f3*)(out + 5 * E);
  float* oi = out + 8 * E;
  float* oj = out + 9 * E;
  for (long i = n + (long)blockIdx.x * blockDim.x + threadIdx.x; i < E;
       i += stride) {
    f3 z{0.f, 0.f, 0.f};
    sr[i] = z;
    oi[i] = -1.0f;
    oj[i] = -1.0f;
  }
}

// K3: idx passthrough (as float), recompute mask, block scan, stable scatter.
__global__ void __launch_bounds__(BLOCK) k3_scatter(
    const float* __restrict__ Rij, const int* __restrict__ idx_i,
    const int* __restrict__ idx_j, const int* __restrict__ offs,
    float* __restrict__ out, long E)
{
  long b = blockIdx.x;
  int t = threadIdx.x;
  long base = b * (long)EPB + (long)t * EPT;
  f3 v[EPT];
  int ii[EPT], jj[EPT];
  unsigned m = 0;
  int cnt = 0;
  if (base < E) {
    const f3* rp = (const f3*)Rij;
#pragma unroll
    for (int k = 0; k < EPT; ++k) v[k] = rp[base + k];
    const int4* ip = (const int4*)(idx_i + base);
    const int4* jp = (const int4*)(idx_j + base);
    int4 ia = ip[0], ib = ip[1], ja = jp[0], jb = jp[1];
    ii[0] = ia.x; ii[1] = ia.y; ii[2] = ia.z; ii[3] = ia.w;
    ii[4] = ib.x; ii[5] = ib.y; ii[6] = ib.z; ii[7] = ib.w;
    jj[0] = ja.x; jj[1] = ja.y; jj[2] = ja.z; jj[3] = ja.w;
    jj[4] = jb.x; jj[5] = jb.y; jj[6] = jb.z; jj[7] = jb.w;
    // passthrough idx as float values
    float4 fi0 = make_float4((float)ii[0], (float)ii[1], (float)ii[2], (float)ii[3]);
    float4 fi1 = make_float4((float)ii[4], (float)ii[5], (float)ii[6], (float)ii[7]);
    float4 fj0 = make_float4((float)jj[0], (float)jj[1], (float)jj[2], (float)jj[3]);
    float4 fj1 = make_float4((float)jj[4], (float)jj[5], (float)jj[6], (float)jj[7]);
    *(float4*)(out + 3 * E + base) = fi0;
    *(float4*)(out + 3 * E + base + 4) = fi1;
    *(float4*)(out + 4 * E + base) = fj0;
    *(float4*)(out + 4 * E + base + 4) = fj1;
#pragma unroll
    for (int k = 0; k < EPT; ++k) {
      float s = sqrtf(v[k].x * v[k].x + v[k].y * v[k].y + v[k].z * v[k].z);
      if (s <= CUTOFF) { m |= 1u << k; ++cnt; }
    }
  }
  int lane = t & 63, wid = t >> 6;
  int sv = cnt;
#pragma unroll
  for (int d = 1; d < 64; d <<= 1) {
    int n = __shfl_up(sv, d, 64);
    if (lane >= d) sv += n;
  }
  __shared__ int wsum[BLOCK / 64];
  if (lane == 63) wsum[wid] = sv;
  __syncthreads();
  int woff = 0;
#pragma unroll
  for (int w = 0; w < BLOCK / 64; ++w)
    if (w < wid) woff += wsum[w];
  long pos = (long)offs[b] + woff + (sv - cnt);
  if (base < E && m) {
    f3* srp = (f3*)(out + 5 * E);
    float* oi = out + 8 * E;
    float* oj = out + 9 * E;
#pragma unroll
    for (int k = 0; k < EPT; ++k) {
      if (m & (1u << k)) {
        srp[pos] = v[k];
        oi[pos] = (float)ii[k];
        oj[pos] = (float)jj[k];
        ++pos;
      }
    }
  }
}

extern "C" void kernel_launch(void* const* d_in, const int* in_sizes, int n_in,
                              void* d_out, int out_size, void* d_ws,
                              size_t ws_size, hipStream_t stream)
{
  const float* Rij = (const float*)d_in[0];
  const int* idx_i = (const int*)d_in[1];
  const int* idx_j = (const int*)d_in[2];
  long E = (long)in_sizes[1];  // idx_i element count
  float* out = (float*)d_out;

  int nb = (int)((E + EPB - 1) / EPB);
  int* counts = (int*)d_ws;        // nb ints
  int* nsr = counts + nb;          // 1 int

  k1_count_copy<<<nb, BLOCK, 0, stream>>>(Rij, out, counts, E);
  k2_scan<<<1, 1024, 0, stream>>>(counts, nb, nsr, out + 10 * E);
  k4_fill<<<2048, 256, 0, stream>>>(out, nsr, E);
  k3_scatter<<<nb, BLOCK, 0, stream>>>(Rij, idx_i, idx_j, counts, out, E);
}